// Round 6
// baseline (179.255 us; speedup 1.0000x reference)
//
#include <hip/hip_runtime.h>

#define G_    32
#define N_    128
#define NP1_  129
#define H_    32
#define EAD_  16
#define MAXD_ 5
#define NE_   65536
#define NPTH_ 1048576

// ---------------------------------------------------------------------------
// Kernel 1: edge encoder into compact eaval[NE][H]; edge_map[(g,i,j)] = e+1.
// one thread per (edge, head); 32 consecutive threads write 128B contiguous.
// ---------------------------------------------------------------------------
__global__ __launch_bounds__(256) void edge_encode_kernel(
    const float* __restrict__ edge_attr,    // [NE][16]
    const int*   __restrict__ edge_index,   // [3][NE]
    const float* __restrict__ edge_enc_w,   // [H][16]
    float*       __restrict__ eaval,        // [NE][H]
    int*         __restrict__ edge_map) {   // [G][N][N], e+1 (0 = empty)
  int t = blockIdx.x * blockDim.x + threadIdx.x;
  if (t >= NE_ * H_) return;
  int e = t >> 5;
  int h = t & 31;
  const float* ea = edge_attr + e * EAD_;
  const float* w  = edge_enc_w + h * EAD_;
  float s = 0.f;
#pragma unroll
  for (int k = 0; k < EAD_; ++k) s += ea[k] * w[k];
  eaval[t] = s;
  if (h == 0) {
    int g = edge_index[e];
    int i = edge_index[NE_ + e];
    int j = edge_index[2 * NE_ + e];
    edge_map[(g * N_ + i) * N_ + j] = e + 1;
  }
}

// ---------------------------------------------------------------------------
// Kernel 2: destination-organized path scatter.
// 1 thread per path: probe edge_map (2MB, L2); survivors (~12.5%) store
// m = e+1 into slot[G][N][N][D]. Destinations unique -> plain stores.
// ---------------------------------------------------------------------------
__global__ __launch_bounds__(256) void path_scatter_kernel(
    const int* __restrict__ path_index,     // [6][NPTH]
    const int* __restrict__ edge_map,       // [G][N][N]
    int*       __restrict__ slot) {         // [G][N][N][MAXD], e+1 (0 empty)
  int p = blockIdx.x * blockDim.x + threadIdx.x;
  int pg = path_index[p];
  int pi = path_index[NPTH_ + p];
  int pj = path_index[2 * NPTH_ + p];
  int pd = path_index[3 * NPTH_ + p];
  int ps = path_index[4 * NPTH_ + p];
  int pt = path_index[5 * NPTH_ + p];
  int m = edge_map[(pg * N_ + ps) * N_ + pt];   // random 4B in 2MB (L2)
  if (m) {
    slot[((pg * N_ + pi) * N_ + pj) * MAXD_ + pd] = m;
  }
}

// ---------------------------------------------------------------------------
// Kernel 3 (fused): per-cell mix + final assembly. One block per (g, a) row.
// Phase A: 8 lane-groups x 16 cells. Per cell j: read 5 slot ints (uniform);
//   per hit, gather eaval row (uniform 128B, L2) and mix with Wd (lane=head);
//   then val[j][h] = spe[sp[j]][h] + aacc*inv -> padded LDS.
// Phase B: write out[g][h][a][:] reading LDS transposed (stride 33).
// ---------------------------------------------------------------------------
__global__ __launch_bounds__(256) void output_fused_kernel(
    const float* __restrict__ attn_bias,    // [G][129][129]
    const int*   __restrict__ spatial_pos,  // [G][N][N]
    const float* __restrict__ spe,          // [512][H]
    const float* __restrict__ virt,         // [H]
    const int*   __restrict__ slot,         // [G][N][N][MAXD]
    const float* __restrict__ eaval,        // [NE][H]
    const float* __restrict__ Wdis,         // edge_dis_emb flat [d][h][k]
    float*       __restrict__ out) {        // [G][H][129][129]
  __shared__ float lds_val[N_ * 33];        // padded: conflict-free transpose
  __shared__ float lds_virt[H_];

  int blk = blockIdx.x;
  int g = blk / NP1_;
  int a = blk - g * NP1_;
  int tid = threadIdx.x;

  if (tid < H_) lds_virt[tid] = virt[tid];

  const float* ab = attn_bias + (g * NP1_ + a) * NP1_;

  if (a == 0) {
    __syncthreads();
    for (int t = tid; t < H_ * NP1_; t += 256) {
      int h = t / NP1_;
      int b = t - h * NP1_;
      out[((g * H_ + h) * NP1_) * NP1_ + b] = 2.f * ab[b] + lds_virt[h];
    }
    return;
  }

  int i = a - 1;
  const int* sp_row   = spatial_pos + (g * N_ + i) * N_;
  const int* slot_row = slot + (size_t)((g * N_ + i) * N_) * MAXD_;

  int grp  = tid >> 5;    // 8 groups
  int lane = tid & 31;    // head index

  // phase A: each group owns 16 consecutive cells
#pragma unroll 1
  for (int it = 0; it < 16; ++it) {
    int j = grp * 16 + it;
    const int* srow = slot_row + j * MAXD_;
    float aacc = 0.f;
#pragma unroll
    for (int d = 0; d < MAXD_; ++d) {
      int m = srow[d];                      // group-uniform load
      if (m) {                              // group-uniform branch
        const float* ea = eaval + (size_t)(m - 1) * H_;
        const float* Wd = Wdis + d * H_ * H_;
        float v0 = 0.f, v1 = 0.f, v2 = 0.f, v3 = 0.f;
#pragma unroll
        for (int h = 0; h < H_; h += 4) {
          v0 += ea[h + 0] * Wd[(h + 0) * H_ + lane];
          v1 += ea[h + 1] * Wd[(h + 1) * H_ + lane];
          v2 += ea[h + 2] * Wd[(h + 2) * H_ + lane];
          v3 += ea[h + 3] * Wd[(h + 3) * H_ + lane];
        }
        aacc += (v0 + v1) + (v2 + v3);
      }
    }
    int s = sp_row[j];                      // group-uniform
    int s2 = (s == 0) ? 1 : s;
    s2 = (s2 > 1) ? s2 - 1 : s2;
    s2 = (s2 > MAXD_) ? MAXD_ : s2;
    float inv = (s2 == 1) ? 1.0f
              : (s2 == 2) ? 0.5f
              : (s2 == 3) ? (1.0f / 3.0f)
              : (s2 == 4) ? 0.25f : 0.2f;
    lds_val[j * 33 + lane] = spe[s * H_ + lane] + aacc * inv;
  }
  __syncthreads();

  // phase B: pure write loop; LDS transposed reads, conflict-free
  for (int t = tid; t < H_ * NP1_; t += 256) {
    int h = t / NP1_;
    int b = t - h * NP1_;
    float val = 2.f * ab[b];
    if (b == 0) {
      val += lds_virt[h];
    } else {
      val += lds_val[(b - 1) * 33 + h];
    }
    out[((g * H_ + h) * NP1_ + a) * NP1_ + b] = val;
  }
}

// ---------------------------------------------------------------------------
extern "C" void kernel_launch(void* const* d_in, const int* in_sizes, int n_in,
                              void* d_out, int out_size, void* d_ws, size_t ws_size,
                              hipStream_t stream) {
  const float* attn_bias   = (const float*)d_in[0];
  const int*   spatial_pos = (const int*)d_in[1];
  const int*   edge_index  = (const int*)d_in[2];
  const float* edge_attr   = (const float*)d_in[3];
  const int*   path_index  = (const int*)d_in[4];
  const float* edge_enc_w  = (const float*)d_in[5];
  const float* spe         = (const float*)d_in[6];
  const float* virt        = (const float*)d_in[7];
  const float* edge_dis    = (const float*)d_in[8];
  float* out = (float*)d_out;

  const size_t SLOT_ELEMS = (size_t)G_ * N_ * N_ * MAXD_;  // 2.62M ints
  const size_t MAP_ELEMS  = (size_t)G_ * N_ * N_;          // 512K ints

  int*   slot     = (int*)d_ws;
  int*   edge_map = slot + SLOT_ELEMS;
  float* eaval    = (float*)(edge_map + MAP_ELEMS);

  // zero slot + edge_map (contiguous, 12.6MB)
  hipMemsetAsync(slot, 0, (SLOT_ELEMS + MAP_ELEMS) * sizeof(int), stream);

  // edge encoder + map
  {
    int total = NE_ * H_;
    edge_encode_kernel<<<(total + 255) / 256, 256, 0, stream>>>(
        edge_attr, edge_index, edge_enc_w, eaval, edge_map);
  }
  // destination-organized path scatter
  path_scatter_kernel<<<NPTH_ / 256, 256, 0, stream>>>(
      path_index, edge_map, slot);
  // fused mix + final output
  output_fused_kernel<<<G_ * NP1_, 256, 0, stream>>>(
      attn_bias, spatial_pos, spe, virt, slot, eaval, edge_dis, out);
}

// Round 7
// 92.086 us; speedup vs baseline: 1.9466x; 1.9466x over previous
//
#include <hip/hip_runtime.h>

#define G_    32
#define N_    128
#define NP1_  129
#define H_    32
#define EAD_  16
#define MAXD_ 5
#define NE_   65536
#define NPTH_ 1048576

// ---------------------------------------------------------------------------
// Kernel 1: edge encoder into compact eaval[NE][H]; edge_map[(g,i,j)] = e+1.
// one thread per (edge, head); 32 consecutive threads write 128B contiguous.
// ---------------------------------------------------------------------------
__global__ __launch_bounds__(256) void edge_encode_kernel(
    const float* __restrict__ edge_attr,    // [NE][16]
    const int*   __restrict__ edge_index,   // [3][NE]
    const float* __restrict__ edge_enc_w,   // [H][16]
    float*       __restrict__ eaval,        // [NE][H]
    int*         __restrict__ edge_map) {   // [G][N][N], e+1 (0 = empty)
  int t = blockIdx.x * blockDim.x + threadIdx.x;
  if (t >= NE_ * H_) return;
  int e = t >> 5;
  int h = t & 31;
  const float* ea = edge_attr + e * EAD_;
  const float* w  = edge_enc_w + h * EAD_;
  float s = 0.f;
#pragma unroll
  for (int k = 0; k < EAD_; ++k) s += ea[k] * w[k];
  eaval[t] = s;
  if (h == 0) {
    int g = edge_index[e];
    int i = edge_index[NE_ + e];
    int j = edge_index[2 * NE_ + e];
    edge_map[(g * N_ + i) * N_ + j] = e + 1;
  }
}

// ---------------------------------------------------------------------------
// Kernel 2: destination-organized path scatter.
// 1 thread per path: probe edge_map (2MB, L2); survivors (~12.5%) store
// m = e+1 into slot[G][N][N][D]. Destinations unique -> plain stores.
// ---------------------------------------------------------------------------
__global__ __launch_bounds__(256) void path_scatter_kernel(
    const int* __restrict__ path_index,     // [6][NPTH]
    const int* __restrict__ edge_map,       // [G][N][N]
    int*       __restrict__ slot) {         // [G][N][N][MAXD], e+1 (0 empty)
  int p = blockIdx.x * blockDim.x + threadIdx.x;
  int pg = path_index[p];
  int pi = path_index[NPTH_ + p];
  int pj = path_index[2 * NPTH_ + p];
  int pd = path_index[3 * NPTH_ + p];
  int ps = path_index[4 * NPTH_ + p];
  int pt = path_index[5 * NPTH_ + p];
  int m = edge_map[(pg * N_ + ps) * N_ + pt];   // random 4B in 2MB (L2)
  if (m) {
    slot[((pg * N_ + pi) * N_ + pj) * MAXD_ + pd] = m;
  }
}

// ---------------------------------------------------------------------------
// Kernel 3 (fused): queue-based per-row mix + final assembly.
// One block per (g, a) row.
// Phase 0: 640 slot ints read COALESCED by 256 threads; hits (~32) pushed
//          to an LDS queue packed as (j<<19 | d<<16 | e).
// Phase A: 8 lane-groups drain the queue; per item one uniform eaval row
//          (8 indep dwordx4, L2/L3) x Wd (L1) -> LDS float atomicAdd into
//          lds_val[j*33+lane] (2-way on wave64 = free).
// Phase A2: val[j][h] = spe[sp[j]][h] + val[j][h]*inv(j)  (coalesced spe).
// Phase B: write out[g][h][a][:] reading LDS transposed (stride 33).
// ---------------------------------------------------------------------------
__global__ __launch_bounds__(256) void output_fused_kernel(
    const float* __restrict__ attn_bias,    // [G][129][129]
    const int*   __restrict__ spatial_pos,  // [G][N][N]
    const float* __restrict__ spe,          // [512][H]
    const float* __restrict__ virt,         // [H]
    const int*   __restrict__ slot,         // [G][N][N][MAXD]
    const float* __restrict__ eaval,        // [NE][H]
    const float* __restrict__ Wdis,         // edge_dis_emb flat [d][h][k]
    float*       __restrict__ out) {        // [G][H][129][129]
  __shared__ float lds_val[N_ * 33];        // padded: conflict-free transpose
  __shared__ float lds_virt[H_];
  __shared__ int   q[N_ * MAXD_];
  __shared__ int   q_cnt;

  int blk = blockIdx.x;
  int g = blk / NP1_;
  int a = blk - g * NP1_;
  int tid = threadIdx.x;

  if (tid < H_) lds_virt[tid] = virt[tid];

  const float* ab = attn_bias + (g * NP1_ + a) * NP1_;

  if (a == 0) {
    __syncthreads();
    for (int t = tid; t < H_ * NP1_; t += 256) {
      int h = t / NP1_;
      int b = t - h * NP1_;
      out[((g * H_ + h) * NP1_) * NP1_ + b] = 2.f * ab[b] + lds_virt[h];
    }
    return;
  }

  int i = a - 1;
  const int* sp_row   = spatial_pos + (g * N_ + i) * N_;
  const int* slot_row = slot + (size_t)((g * N_ + i) * N_) * MAXD_;

  // zero the accumulator tile; init queue
  for (int t = tid; t < N_ * 33; t += 256) lds_val[t] = 0.f;
  if (tid == 0) q_cnt = 0;
  __syncthreads();

  // phase 0: coalesced slot scan -> LDS queue (640 ints, 2.5 loads/thread)
  for (int f = tid; f < N_ * MAXD_; f += 256) {
    int m = slot_row[f];
    if (m) {
      int j = f / MAXD_;
      int d = f - j * MAXD_;
      int idx = atomicAdd(&q_cnt, 1);             // LDS atomic
      q[idx] = (j << 19) | (d << 16) | (m - 1);
    }
  }
  __syncthreads();
  int cnt = q_cnt;

  // phase A: 8 lane-groups drain the queue (~4 items each)
  int grp  = tid >> 5;
  int lane = tid & 31;
  for (int s = grp; s < cnt; s += 8) {
    int ent = q[s];
    int j = ent >> 19;
    int d = (ent >> 16) & 7;
    int e = ent & 0xFFFF;
    const float* ea = eaval + (size_t)e * H_;     // group-uniform row
    const float* Wd = Wdis + d * (H_ * H_);       // 20KB total, L1-resident
    float v0 = 0.f, v1 = 0.f, v2 = 0.f, v3 = 0.f;
#pragma unroll
    for (int h = 0; h < H_; h += 4) {
      v0 += ea[h + 0] * Wd[(h + 0) * H_ + lane];
      v1 += ea[h + 1] * Wd[(h + 1) * H_ + lane];
      v2 += ea[h + 2] * Wd[(h + 2) * H_ + lane];
      v3 += ea[h + 3] * Wd[(h + 3) * H_ + lane];
    }
    atomicAdd(&lds_val[j * 33 + lane], (v0 + v1) + (v2 + v3));
  }
  __syncthreads();

  // phase A2: add spatial embedding, apply path-length normalizer
  for (int t = tid; t < N_ * H_; t += 256) {
    int j = t >> 5;
    int h = t & 31;
    int s = sp_row[j];                      // group-uniform
    int s2 = (s == 0) ? 1 : s;
    s2 = (s2 > 1) ? s2 - 1 : s2;
    s2 = (s2 > MAXD_) ? MAXD_ : s2;
    float inv = (s2 == 1) ? 1.0f
              : (s2 == 2) ? 0.5f
              : (s2 == 3) ? (1.0f / 3.0f)
              : (s2 == 4) ? 0.25f : 0.2f;
    lds_val[j * 33 + h] = spe[s * H_ + h] + lds_val[j * 33 + h] * inv;
  }
  __syncthreads();

  // phase B: pure write loop; LDS transposed reads, conflict-free
  for (int t = tid; t < H_ * NP1_; t += 256) {
    int h = t / NP1_;
    int b = t - h * NP1_;
    float val = 2.f * ab[b];
    if (b == 0) {
      val += lds_virt[h];
    } else {
      val += lds_val[(b - 1) * 33 + h];
    }
    out[((g * H_ + h) * NP1_ + a) * NP1_ + b] = val;
  }
}

// ---------------------------------------------------------------------------
extern "C" void kernel_launch(void* const* d_in, const int* in_sizes, int n_in,
                              void* d_out, int out_size, void* d_ws, size_t ws_size,
                              hipStream_t stream) {
  const float* attn_bias   = (const float*)d_in[0];
  const int*   spatial_pos = (const int*)d_in[1];
  const int*   edge_index  = (const int*)d_in[2];
  const float* edge_attr   = (const float*)d_in[3];
  const int*   path_index  = (const int*)d_in[4];
  const float* edge_enc_w  = (const float*)d_in[5];
  const float* spe         = (const float*)d_in[6];
  const float* virt        = (const float*)d_in[7];
  const float* edge_dis    = (const float*)d_in[8];
  float* out = (float*)d_out;

  const size_t SLOT_ELEMS = (size_t)G_ * N_ * N_ * MAXD_;  // 2.62M ints
  const size_t MAP_ELEMS  = (size_t)G_ * N_ * N_;          // 512K ints

  int*   slot     = (int*)d_ws;
  int*   edge_map = slot + SLOT_ELEMS;
  float* eaval    = (float*)(edge_map + MAP_ELEMS);

  // zero slot + edge_map (contiguous, 12.6MB)
  hipMemsetAsync(slot, 0, (SLOT_ELEMS + MAP_ELEMS) * sizeof(int), stream);

  // edge encoder + map
  {
    int total = NE_ * H_;
    edge_encode_kernel<<<(total + 255) / 256, 256, 0, stream>>>(
        edge_attr, edge_index, edge_enc_w, eaval, edge_map);
  }
  // destination-organized path scatter
  path_scatter_kernel<<<NPTH_ / 256, 256, 0, stream>>>(
      path_index, edge_map, slot);
  // fused queue mix + final output
  output_fused_kernel<<<G_ * NP1_, 256, 0, stream>>>(
      attn_bias, spatial_pos, spe, virt, slot, eaval, edge_dis, out);
}